// Round 9
// baseline (1929.286 us; speedup 1.0000x reference)
//
#include <hip/hip_runtime.h>
#include <hip/hip_bf16.h>

typedef unsigned int uint;
typedef unsigned short ushort;

#define NN 65536
#define NE 1048576
#define DD 128
#define TOTE (NE + NN)   // 1114112

__device__ __forceinline__ float b2f(ushort u) {
    uint v = ((uint)u) << 16; float f; __builtin_memcpy(&f, &v, 4); return f;
}
__device__ __forceinline__ ushort f2b(float f) {
    uint x; __builtin_memcpy(&x, &f, 4);
    uint r = (x + 0x7fffu + ((x >> 16) & 1u)) >> 16;
    return (ushort)r;
}

typedef __bf16 bf16x8 __attribute__((ext_vector_type(8)));
typedef float f32x4 __attribute__((ext_vector_type(4)));

// ---------- init: transpose W (fp32 k-major -> bf16 n-major) + zero cnt/sumbuf ----------
__global__ void k_init(const float* __restrict__ Wl, const float* __restrict__ Wr,
                       ushort* __restrict__ WT, int* __restrict__ cnt, float* __restrict__ sumbuf) {
    // grid (128, 2, 3), block 128
    int k = blockIdx.x, n = threadIdx.x, lr = blockIdx.y, layer = blockIdx.z;
    const float* W = (lr ? Wr : Wl) + layer * 16384;
    WT[(layer * 2 + lr) * 16384 + n * 128 + k] = f2b(W[k * 128 + n]);
    int gid = ((blockIdx.z * 2 + blockIdx.y) * 128 + blockIdx.x) * 128 + threadIdx.x;
    if (gid < NN) cnt[gid] = 0;
    if (gid == NN) sumbuf[0] = 0.f;
}

// ---------- histogram by dst (+self loops) fused with edge_attr sum ----------
__global__ void k_histsum(const int* __restrict__ dst, const float* __restrict__ ea,
                          int* __restrict__ cnt, float* __restrict__ sum) {
    __shared__ float red[256];
    int t = threadIdx.x;
    int e = blockIdx.x * 256 + t;     // grid covers TOTE exactly
    int d = (e < NE) ? dst[e] : (e - NE);
    atomicAdd(&cnt[d], 1);
    float s = (e < NE) ? ea[e] : 0.f;
    red[t] = s; __syncthreads();
    for (int o = 128; o > 0; o >>= 1) { if (t < o) red[t] += red[t + o]; __syncthreads(); }
    if (t == 0 && red[0] != 0.f) atomicAdd(sum, red[0]);
}

__global__ void k_scanA(const int* __restrict__ cnt, int* __restrict__ row_off, int* __restrict__ bsum) {
    __shared__ int tmp[256];
    int t = threadIdx.x, i = blockIdx.x * 256 + t;
    int v = cnt[i]; tmp[t] = v; __syncthreads();
    for (int off = 1; off < 256; off <<= 1) {
        int x = (t >= off) ? tmp[t - off] : 0;
        __syncthreads();
        tmp[t] += x;
        __syncthreads();
    }
    row_off[i] = tmp[t] - v;
    if (t == 255) bsum[blockIdx.x] = tmp[255];
}

// scanC with local re-scan of bsum (eliminates scanB dispatch)
__global__ void k_scanC(int* __restrict__ row_off, const int* __restrict__ bsum, int* __restrict__ cursor) {
    __shared__ int tmp[256];
    __shared__ int excl[256];
    int t = threadIdx.x;
    int v = bsum[t]; tmp[t] = v; __syncthreads();
    for (int off = 1; off < 256; off <<= 1) {
        int x = (t >= off) ? tmp[t - off] : 0;
        __syncthreads();
        tmp[t] += x;
        __syncthreads();
    }
    excl[t] = tmp[t] - v;
    __syncthreads();
    int offb = excl[blockIdx.x];
    int i = blockIdx.x * 256 + t;
    int nv = row_off[i] + offb;
    row_off[i] = nv;
    cursor[i] = nv;
    if (i == 0) row_off[NN] = TOTE;
}

__global__ void k_scatter(const int* __restrict__ src, const int* __restrict__ dst,
                          const float* __restrict__ ea, const float* __restrict__ sum,
                          int* __restrict__ cursor, int2* __restrict__ adj) {
    int e = blockIdx.x * 256 + threadIdx.x;
    int s, d; float a;
    if (e < NE) { s = src[e]; d = dst[e]; a = ea[e]; }
    else        { s = e - NE; d = s;      a = sum[0] * (1.0f / NE); }
    int pos = atomicAdd(&cursor[d], 1);
    adj[pos] = make_int2(s, __float_as_int(a));
}

// ---------- dual GEMM: xl = src@Wl + bl, xr = src@Wr + br  (bf16 MFMA 16x16x32) ----------
// R7 orientation: D row = node, col = channel; 2B stores in 32B-contiguous quad chunks.
#define LDA 136   // bf16 elems per A row in LDS (272B stride, 16B aligned)

template<bool F32SRC>
__global__ __launch_bounds__(256) void k_gemm(const void* __restrict__ srcv, const ushort* __restrict__ WT,
                                              const float* __restrict__ bl, const float* __restrict__ br,
                                              ushort* __restrict__ xl, ushort* __restrict__ xr) {
    __shared__ ushort A[64 * LDA];
    int t = threadIdx.x;
    int rowbase = blockIdx.x * 64;

    if (F32SRC) {
        const float* src = (const float*)srcv;
        #pragma unroll
        for (int it = 0; it < 8; it++) {
            int idx = it * 256 + t;          // 2048 chunks of 4 floats
            int r = idx >> 5, cc = (idx & 31) * 4;
            float4 v = *(const float4*)&src[(size_t)(rowbase + r) * 128 + cc];
            ushort4 pk; pk.x = f2b(v.x); pk.y = f2b(v.y); pk.z = f2b(v.z); pk.w = f2b(v.w);
            *(ushort4*)&A[r * LDA + cc] = pk;
        }
    } else {
        const ushort* src = (const ushort*)srcv;
        #pragma unroll
        for (int it = 0; it < 4; it++) {
            int idx = it * 256 + t;          // 1024 chunks of 8 bf16
            int r = idx >> 4, cc = (idx & 15) * 8;
            *(bf16x8*)&A[r * LDA + cc] = *(const bf16x8*)&src[(size_t)(rowbase + r) * 128 + cc];
        }
    }
    __syncthreads();

    int wave = t >> 6, lane = t & 63;
    int row16 = lane & 15, quad = lane >> 4;

    f32x4 accl[8], accr[8];
    for (int i = 0; i < 8; i++) {
        accl[i] = (f32x4){0.f, 0.f, 0.f, 0.f};
        accr[i] = (f32x4){0.f, 0.f, 0.f, 0.f};
    }

    for (int ks = 0; ks < 4; ks++) {
        bf16x8 a = *(const bf16x8*)&A[(wave * 16 + row16) * LDA + ks * 32 + quad * 8];
        for (int tc = 0; tc < 8; tc++) {
            int coln = tc * 16 + row16;                 // B fragment: n = lane&15
            bf16x8 b_l = *(const bf16x8*)&WT[coln * 128 + ks * 32 + quad * 8];
            bf16x8 b_r = *(const bf16x8*)&WT[16384 + coln * 128 + ks * 32 + quad * 8];
            accl[tc] = __builtin_amdgcn_mfma_f32_16x16x32_bf16(a, b_l, accl[tc], 0, 0, 0);
            accr[tc] = __builtin_amdgcn_mfma_f32_16x16x32_bf16(a, b_r, accr[tc], 0, 0, 0);
        }
    }

    for (int tc = 0; tc < 8; tc++) {
        int col = tc * 16 + row16;                      // C/D: col = lane&15
        float bbl = bl[col], bbr = br[col];
        for (int r = 0; r < 4; r++) {
            int row = rowbase + wave * 16 + quad * 4 + r;   // C/D: row = quad*4 + reg
            size_t o = (size_t)row * 128 + col;
            xl[o] = f2b(accl[tc][r] + bbl);
            xr[o] = f2b(accr[tc][r] + bbr);
        }
    }
}

// ---------- fused attention, single-gather, max-free softmax ----------
// One wave per node. Lane = (p=lane>>3: edge slot, cl=lane&7: 16-ch block).
// Logits structurally bounded -> exp(a) directly, no running max/corr chain.
template<int H, bool FINAL>
__global__ __launch_bounds__(256, 8) void k_attn(
    const ushort* __restrict__ xl, const ushort* __restrict__ xr,
    const int* __restrict__ row_off, const int2* __restrict__ adj,
    const float* __restrict__ We, const float* __restrict__ att,
    const float* __restrict__ bias, const float* __restrict__ ln_g, const float* __restrict__ ln_b,
    const float* __restrict__ hin, float* __restrict__ hout, ushort* __restrict__ hb,
    float* __restrict__ outp)
{
    __shared__ float red_s[4][128];

    int wave = threadIdx.x >> 6, lane = threadIdx.x & 63;
    int n = blockIdx.x * 4 + wave;
    int p = lane >> 3;          // edge slot within 8-edge group
    int cl = lane & 7;          // channel block: ch [16*cl, 16*cl+16)
    int c16 = cl * 16;

    // register caches
    float we[16], at[16], xrl[16];
    #pragma unroll
    for (int k = 0; k < 16; k++) { we[k] = We[c16 + k]; at[k] = att[c16 + k]; }
    {
        bf16x8 r0 = *(const bf16x8*)&xr[(size_t)n * 128 + c16];
        bf16x8 r1 = *(const bf16x8*)&xr[(size_t)n * 128 + c16 + 8];
        #pragma unroll
        for (int k = 0; k < 8; k++) { xrl[k] = (float)r0[k]; xrl[8 + k] = (float)r1[k]; }
    }

    int s0 = row_off[n], s1 = row_off[n + 1];
    int iters = (s1 - s0 + 7) >> 3;     // >= 1 (self-loop)

    float l_run = 0.f;
    float acc[16];
    #pragma unroll
    for (int k = 0; k < 16; k++) acc[k] = 0.f;

    // prefetch group 0
    int j0 = s0 + p;
    int ja = (j0 < s1) ? j0 : s0;
    int2 pk0 = adj[ja];
    float ea_n = (j0 < s1) ? __int_as_float(pk0.y) : 0.f;
    bf16x8 nx0 = *(const bf16x8*)&xl[(size_t)pk0.x * 128 + c16];
    bf16x8 nx1 = *(const bf16x8*)&xl[(size_t)pk0.x * 128 + c16 + 8];

    for (int it = 0; it < iters; ++it) {
        bf16x8 x0 = nx0, x1 = nx1;
        float ea_c = ea_n;
        bool valid = (s0 + it * 8 + p) < s1;

        // prefetch next group
        if (it + 1 < iters) {
            int jn = s0 + (it + 1) * 8 + p;
            int jb = (jn < s1) ? jn : s0;
            int2 pk = adj[jb];
            ea_n = (jn < s1) ? __int_as_float(pk.y) : 0.f;
            nx0 = *(const bf16x8*)&xl[(size_t)pk.x * 128 + c16];
            nx1 = *(const bf16x8*)&xl[(size_t)pk.x * 128 + c16 + 8];
        }

        // convert + logit partial over this lane's 16 channels
        float xf[16];
        #pragma unroll
        for (int k = 0; k < 8; k++) { xf[k] = (float)x0[k]; xf[8 + k] = (float)x1[k]; }
        float s = 0.f;
        #pragma unroll
        for (int k = 0; k < 16; k++) {
            float m = xf[k] + fmaf(ea_c, we[k], xrl[k]);
            m = fmaxf(m, 0.2f * m);             // leaky_relu(0.2)
            s = fmaf(m, at[k], s);
        }
        // head reduction across cl lanes of same edge
        s += __shfl_xor(s, 1);
        if (H == 1) { s += __shfl_xor(s, 2); s += __shfl_xor(s, 4); }
        if (!valid) s = -1e30f;

        float e = __expf(s);                 // 0 for invalid; no overflow (|s| small)
        l_run += e;
        #pragma unroll
        for (int k = 0; k < 16; k++) acc[k] = fmaf(e, xf[k], acc[k]);
    }

    // reduce l and acc over the 8 edge slots (p)
    l_run += __shfl_xor(l_run, 8);
    l_run += __shfl_xor(l_run, 16);
    l_run += __shfl_xor(l_run, 32);
    float inv = 1.0f / (l_run + 1e-16f);
    #pragma unroll
    for (int k = 0; k < 16; k++) {
        acc[k] += __shfl_xor(acc[k], 8);
        acc[k] += __shfl_xor(acc[k], 16);
        acc[k] += __shfl_xor(acc[k], 32);
    }

    // redistribute to 2-channels-per-lane layout via LDS (within-wave)
    if (p == 0) {
        #pragma unroll
        for (int k = 0; k < 16; k += 2)
            *(float2*)&red_s[wave][c16 + k] = make_float2(acc[k] * inv, acc[k + 1] * inv);
    }
    int c0 = 2 * lane;
    float2 ov = *(float2*)&red_s[wave][c0];
    float o0 = ov.x + bias[c0];
    float o1 = ov.y + bias[c0 + 1];

    // LayerNorm over 128 channels (2 per lane)
    float sred = o0 + o1;
    #pragma unroll
    for (int off = 1; off < 64; off <<= 1) sred += __shfl_xor(sred, off);
    float mu = sred * (1.f / 128.f);
    float d0 = o0 - mu, d1 = o1 - mu;
    float v = d0 * d0 + d1 * d1;
    #pragma unroll
    for (int off = 1; off < 64; off <<= 1) v += __shfl_xor(v, off);
    float rstd = rsqrtf(v * (1.f / 128.f) + 1e-5f);
    o0 = d0 * rstd * ln_g[c0] + ln_b[c0];
    o1 = d1 * rstd * ln_g[c0 + 1] + ln_b[c0 + 1];

    float2 hv = *(const float2*)&hin[(size_t)n * 128 + c0];
    if (FINAL) {
        float r0 = hv.x + o0, r1 = hv.y + o1;
        int g = n >> 9, rr = n & 511;
        if (rr < 511)
            *(float2*)&outp[((size_t)(g * 511 + rr)) * 128 + c0] = make_float2(r0, r1);
    } else {
        o0 = 0.5f * o0 * (1.f + erff(o0 * 0.70710678118f));   // exact GELU
        o1 = 0.5f * o1 * (1.f + erff(o1 * 0.70710678118f));
        hv.x += o0; hv.y += o1;
        *(float2*)&hout[(size_t)n * 128 + c0] = hv;
        uint pk = (uint)f2b(hv.x) | ((uint)f2b(hv.y) << 16);
        *(uint*)&hb[(size_t)n * 128 + c0] = pk;
    }
}

extern "C" void kernel_launch(void* const* d_in, const int* in_sizes, int n_in,
                              void* d_out, int out_size, void* d_ws, size_t ws_size,
                              hipStream_t stream) {
    const float* x        = (const float*)d_in[0];
    const int*   edge_src = (const int*)d_in[1];
    const int*   edge_dst = (const int*)d_in[2];
    const float* edge_attr= (const float*)d_in[3];
    const float* Wl       = (const float*)d_in[4];
    const float* bl       = (const float*)d_in[5];
    const float* Wr       = (const float*)d_in[6];
    const float* br       = (const float*)d_in[7];
    const float* We       = (const float*)d_in[8];
    const float* att      = (const float*)d_in[9];
    const float* bias_p   = (const float*)d_in[10];
    const float* ln_g     = (const float*)d_in[11];
    const float* ln_b     = (const float*)d_in[12];
    float* out = (float*)d_out;

    char* ws = (char*)d_ws;
    float*  h       = (float*)(ws + 0);                 // 33,554,432
    ushort* hb      = (ushort*)(ws + 33554432);         // 16,777,216
    ushort* xl      = (ushort*)(ws + 50331648);         // 16,777,216
    ushort* xr      = (ushort*)(ws + 67108864);         // 16,777,216
    int2*   adj     = (int2*)(ws + 83886080);           //  8,912,896
    int*    row_off = (int*)(ws + 92798976);            //    262,400 (incl pad)
    int*    cnt     = (int*)(ws + 93061376);            //    262,144 (also cursor)
    int*    bsum    = (int*)(ws + 93323520);            //      1,024
    float*  sumbuf  = (float*)(ws + 93324544);          //        256
    ushort* WT      = (ushort*)(ws + 93324800);         //    196,608 (3 layers x 2)

    // 1: transpose weights + zero cnt/sumbuf
    k_init<<<dim3(128, 2, 3), 128, 0, stream>>>(Wl, Wr, WT, cnt, sumbuf);
    // 2: histogram + edge_attr sum
    k_histsum<<<TOTE / 256, 256, 0, stream>>>(edge_dst, edge_attr, cnt, sumbuf);
    // 3-4: scan
    k_scanA<<<NN / 256, 256, 0, stream>>>(cnt, row_off, bsum);
    k_scanC<<<NN / 256, 256, 0, stream>>>(row_off, bsum, cnt);
    // 5: scatter
    k_scatter<<<TOTE / 256, 256, 0, stream>>>(edge_src, edge_dst, edge_attr, sumbuf, cnt, adj);

    // layer 0: GEMM from fp32 x; residual from x
    k_gemm<true><<<NN / 64, 256, 0, stream>>>(x, WT, bl, br, xl, xr);
    k_attn<4, false><<<NN / 4, 256, 0, stream>>>(xl, xr, row_off, adj,
                                                 We, att, bias_p, ln_g, ln_b,
                                                 x, h, hb, nullptr);
    // layer 1
    k_gemm<false><<<NN / 64, 256, 0, stream>>>(hb, WT + 32768, bl + 128, br + 128, xl, xr);
    k_attn<4, false><<<NN / 4, 256, 0, stream>>>(xl, xr, row_off, adj,
                                                 We + 128, att + 128, bias_p + 128,
                                                 ln_g + 128, ln_b + 128,
                                                 h, h, hb, nullptr);
    // layer 2 (final): writes out directly, drops virtual node
    k_gemm<false><<<NN / 64, 256, 0, stream>>>(hb, WT + 65536, bl + 256, br + 256, xl, xr);
    k_attn<1, true><<<NN / 4, 256, 0, stream>>>(xl, xr, row_off, adj,
                                                We + 256, att + 256, bias_p + 256,
                                                ln_g + 256, ln_b + 256,
                                                h, nullptr, nullptr, out);
}

// Round 10
// 670.485 us; speedup vs baseline: 2.8774x; 2.8774x over previous
//
#include <hip/hip_runtime.h>
#include <hip/hip_bf16.h>

typedef unsigned int uint;
typedef unsigned short ushort;

#define NN 65536
#define NE 1048576
#define DD 128
#define TOTE (NE + NN)   // 1114112

__device__ __forceinline__ float b2f(ushort u) {
    uint v = ((uint)u) << 16; float f; __builtin_memcpy(&f, &v, 4); return f;
}
__device__ __forceinline__ ushort f2b(float f) {
    uint x; __builtin_memcpy(&x, &f, 4);
    uint r = (x + 0x7fffu + ((x >> 16) & 1u)) >> 16;
    return (ushort)r;
}

typedef __bf16 bf16x8 __attribute__((ext_vector_type(8)));
typedef float f32x4 __attribute__((ext_vector_type(4)));

// ---------- init: transpose W (fp32 k-major -> bf16 n-major) + zero cnt/sumbuf ----------
__global__ void k_init(const float* __restrict__ Wl, const float* __restrict__ Wr,
                       ushort* __restrict__ WT, int* __restrict__ cnt, float* __restrict__ sumbuf) {
    // grid (128, 2, 3), block 128
    int k = blockIdx.x, n = threadIdx.x, lr = blockIdx.y, layer = blockIdx.z;
    const float* W = (lr ? Wr : Wl) + layer * 16384;
    WT[(layer * 2 + lr) * 16384 + n * 128 + k] = f2b(W[k * 128 + n]);
    int gid = ((blockIdx.z * 2 + blockIdx.y) * 128 + blockIdx.x) * 128 + threadIdx.x;
    if (gid < NN) cnt[gid] = 0;
    if (gid == NN) sumbuf[0] = 0.f;
}

// ---------- histogram by dst (+self loops) fused with edge_attr sum ----------
__global__ void k_histsum(const int* __restrict__ dst, const float* __restrict__ ea,
                          int* __restrict__ cnt, float* __restrict__ sum) {
    __shared__ float red[256];
    int t = threadIdx.x;
    int e = blockIdx.x * 256 + t;     // grid covers TOTE exactly
    int d = (e < NE) ? dst[e] : (e - NE);
    atomicAdd(&cnt[d], 1);
    float s = (e < NE) ? ea[e] : 0.f;
    red[t] = s; __syncthreads();
    for (int o = 128; o > 0; o >>= 1) { if (t < o) red[t] += red[t + o]; __syncthreads(); }
    if (t == 0 && red[0] != 0.f) atomicAdd(sum, red[0]);
}

__global__ void k_scanA(const int* __restrict__ cnt, int* __restrict__ row_off, int* __restrict__ bsum) {
    __shared__ int tmp[256];
    int t = threadIdx.x, i = blockIdx.x * 256 + t;
    int v = cnt[i]; tmp[t] = v; __syncthreads();
    for (int off = 1; off < 256; off <<= 1) {
        int x = (t >= off) ? tmp[t - off] : 0;
        __syncthreads();
        tmp[t] += x;
        __syncthreads();
    }
    row_off[i] = tmp[t] - v;
    if (t == 255) bsum[blockIdx.x] = tmp[255];
}

// scanC with local re-scan of bsum (eliminates scanB dispatch)
__global__ void k_scanC(int* __restrict__ row_off, const int* __restrict__ bsum, int* __restrict__ cursor) {
    __shared__ int tmp[256];
    __shared__ int excl[256];
    int t = threadIdx.x;
    int v = bsum[t]; tmp[t] = v; __syncthreads();
    for (int off = 1; off < 256; off <<= 1) {
        int x = (t >= off) ? tmp[t - off] : 0;
        __syncthreads();
        tmp[t] += x;
        __syncthreads();
    }
    excl[t] = tmp[t] - v;
    __syncthreads();
    int offb = excl[blockIdx.x];
    int i = blockIdx.x * 256 + t;
    int nv = row_off[i] + offb;
    row_off[i] = nv;
    cursor[i] = nv;
    if (i == 0) row_off[NN] = TOTE;
}

__global__ void k_scatter(const int* __restrict__ src, const int* __restrict__ dst,
                          const float* __restrict__ ea, const float* __restrict__ sum,
                          int* __restrict__ cursor, int2* __restrict__ adj) {
    int e = blockIdx.x * 256 + threadIdx.x;
    int s, d; float a;
    if (e < NE) { s = src[e]; d = dst[e]; a = ea[e]; }
    else        { s = e - NE; d = s;      a = sum[0] * (1.0f / NE); }
    int pos = atomicAdd(&cursor[d], 1);
    adj[pos] = make_int2(s, __float_as_int(a));
}

// ---------- dual GEMM: xl = src@Wl + bl, xr = src@Wr + br  (bf16 MFMA 16x16x32) ----------
// R7 orientation: D row = node, col = channel; 2B stores in 32B-contiguous quad chunks.
#define LDA 136   // bf16 elems per A row in LDS (272B stride, 16B aligned)

template<bool F32SRC>
__global__ __launch_bounds__(256) void k_gemm(const void* __restrict__ srcv, const ushort* __restrict__ WT,
                                              const float* __restrict__ bl, const float* __restrict__ br,
                                              ushort* __restrict__ xl, ushort* __restrict__ xr) {
    __shared__ ushort A[64 * LDA];
    int t = threadIdx.x;
    int rowbase = blockIdx.x * 64;

    if (F32SRC) {
        const float* src = (const float*)srcv;
        #pragma unroll
        for (int it = 0; it < 8; it++) {
            int idx = it * 256 + t;          // 2048 chunks of 4 floats
            int r = idx >> 5, cc = (idx & 31) * 4;
            float4 v = *(const float4*)&src[(size_t)(rowbase + r) * 128 + cc];
            ushort4 pk; pk.x = f2b(v.x); pk.y = f2b(v.y); pk.z = f2b(v.z); pk.w = f2b(v.w);
            *(ushort4*)&A[r * LDA + cc] = pk;
        }
    } else {
        const ushort* src = (const ushort*)srcv;
        #pragma unroll
        for (int it = 0; it < 4; it++) {
            int idx = it * 256 + t;          // 1024 chunks of 8 bf16
            int r = idx >> 4, cc = (idx & 15) * 8;
            *(bf16x8*)&A[r * LDA + cc] = *(const bf16x8*)&src[(size_t)(rowbase + r) * 128 + cc];
        }
    }
    __syncthreads();

    int wave = t >> 6, lane = t & 63;
    int row16 = lane & 15, quad = lane >> 4;

    f32x4 accl[8], accr[8];
    for (int i = 0; i < 8; i++) {
        accl[i] = (f32x4){0.f, 0.f, 0.f, 0.f};
        accr[i] = (f32x4){0.f, 0.f, 0.f, 0.f};
    }

    for (int ks = 0; ks < 4; ks++) {
        bf16x8 a = *(const bf16x8*)&A[(wave * 16 + row16) * LDA + ks * 32 + quad * 8];
        for (int tc = 0; tc < 8; tc++) {
            int coln = tc * 16 + row16;                 // B fragment: n = lane&15
            bf16x8 b_l = *(const bf16x8*)&WT[coln * 128 + ks * 32 + quad * 8];
            bf16x8 b_r = *(const bf16x8*)&WT[16384 + coln * 128 + ks * 32 + quad * 8];
            accl[tc] = __builtin_amdgcn_mfma_f32_16x16x32_bf16(a, b_l, accl[tc], 0, 0, 0);
            accr[tc] = __builtin_amdgcn_mfma_f32_16x16x32_bf16(a, b_r, accr[tc], 0, 0, 0);
        }
    }

    for (int tc = 0; tc < 8; tc++) {
        int col = tc * 16 + row16;                      // C/D: col = lane&15
        float bbl = bl[col], bbr = br[col];
        for (int r = 0; r < 4; r++) {
            int row = rowbase + wave * 16 + quad * 4 + r;   // C/D: row = quad*4 + reg
            size_t o = (size_t)row * 128 + col;
            xl[o] = f2b(accl[tc][r] + bbl);
            xr[o] = f2b(accr[tc][r] + bbr);
        }
    }
}

// ---------- fused attention, single-gather, max-free softmax ----------
// One wave per node. Lane = (p=lane>>3: edge slot, cl=lane&7: 16-ch block).
// Logits structurally bounded -> exp(a) directly, no running max/corr chain.
// NOTE: (256,4) — (256,8) forces VGPR<=32 and spills ~50 live regs (R9: 2.4GB
// scratch traffic, 3x regression). 60 VGPR needs min-waves<=4.
template<int H, bool FINAL>
__global__ __launch_bounds__(256, 4) void k_attn(
    const ushort* __restrict__ xl, const ushort* __restrict__ xr,
    const int* __restrict__ row_off, const int2* __restrict__ adj,
    const float* __restrict__ We, const float* __restrict__ att,
    const float* __restrict__ bias, const float* __restrict__ ln_g, const float* __restrict__ ln_b,
    const float* __restrict__ hin, float* __restrict__ hout, ushort* __restrict__ hb,
    float* __restrict__ outp)
{
    __shared__ float red_s[4][128];

    int wave = threadIdx.x >> 6, lane = threadIdx.x & 63;
    int n = blockIdx.x * 4 + wave;
    int p = lane >> 3;          // edge slot within 8-edge group
    int cl = lane & 7;          // channel block: ch [16*cl, 16*cl+16)
    int c16 = cl * 16;

    // register caches
    float we[16], at[16], xrl[16];
    #pragma unroll
    for (int k = 0; k < 16; k++) { we[k] = We[c16 + k]; at[k] = att[c16 + k]; }
    {
        bf16x8 r0 = *(const bf16x8*)&xr[(size_t)n * 128 + c16];
        bf16x8 r1 = *(const bf16x8*)&xr[(size_t)n * 128 + c16 + 8];
        #pragma unroll
        for (int k = 0; k < 8; k++) { xrl[k] = (float)r0[k]; xrl[8 + k] = (float)r1[k]; }
    }

    int s0 = row_off[n], s1 = row_off[n + 1];
    int iters = (s1 - s0 + 7) >> 3;     // >= 1 (self-loop)

    float l_run = 0.f;
    float acc[16];
    #pragma unroll
    for (int k = 0; k < 16; k++) acc[k] = 0.f;

    // prefetch group 0
    int j0 = s0 + p;
    int ja = (j0 < s1) ? j0 : s0;
    int2 pk0 = adj[ja];
    float ea_n = (j0 < s1) ? __int_as_float(pk0.y) : 0.f;
    bf16x8 nx0 = *(const bf16x8*)&xl[(size_t)pk0.x * 128 + c16];
    bf16x8 nx1 = *(const bf16x8*)&xl[(size_t)pk0.x * 128 + c16 + 8];

    for (int it = 0; it < iters; ++it) {
        bf16x8 x0 = nx0, x1 = nx1;
        float ea_c = ea_n;
        bool valid = (s0 + it * 8 + p) < s1;

        // prefetch next group
        if (it + 1 < iters) {
            int jn = s0 + (it + 1) * 8 + p;
            int jb = (jn < s1) ? jn : s0;
            int2 pk = adj[jb];
            ea_n = (jn < s1) ? __int_as_float(pk.y) : 0.f;
            nx0 = *(const bf16x8*)&xl[(size_t)pk.x * 128 + c16];
            nx1 = *(const bf16x8*)&xl[(size_t)pk.x * 128 + c16 + 8];
        }

        // convert + logit partial over this lane's 16 channels
        float xf[16];
        #pragma unroll
        for (int k = 0; k < 8; k++) { xf[k] = (float)x0[k]; xf[8 + k] = (float)x1[k]; }
        float s = 0.f;
        #pragma unroll
        for (int k = 0; k < 16; k++) {
            float m = xf[k] + fmaf(ea_c, we[k], xrl[k]);
            m = fmaxf(m, 0.2f * m);             // leaky_relu(0.2)
            s = fmaf(m, at[k], s);
        }
        // head reduction across cl lanes of same edge
        s += __shfl_xor(s, 1);
        if (H == 1) { s += __shfl_xor(s, 2); s += __shfl_xor(s, 4); }
        if (!valid) s = -1e30f;

        float e = __expf(s);                 // 0 for invalid; no overflow (|s| small)
        l_run += e;
        #pragma unroll
        for (int k = 0; k < 16; k++) acc[k] = fmaf(e, xf[k], acc[k]);
    }

    // reduce l and acc over the 8 edge slots (p)
    l_run += __shfl_xor(l_run, 8);
    l_run += __shfl_xor(l_run, 16);
    l_run += __shfl_xor(l_run, 32);
    float inv = 1.0f / (l_run + 1e-16f);
    #pragma unroll
    for (int k = 0; k < 16; k++) {
        acc[k] += __shfl_xor(acc[k], 8);
        acc[k] += __shfl_xor(acc[k], 16);
        acc[k] += __shfl_xor(acc[k], 32);
    }

    // redistribute to 2-channels-per-lane layout via LDS (within-wave)
    if (p == 0) {
        #pragma unroll
        for (int k = 0; k < 16; k += 2)
            *(float2*)&red_s[wave][c16 + k] = make_float2(acc[k] * inv, acc[k + 1] * inv);
    }
    int c0 = 2 * lane;
    float2 ov = *(float2*)&red_s[wave][c0];
    float o0 = ov.x + bias[c0];
    float o1 = ov.y + bias[c0 + 1];

    // LayerNorm over 128 channels (2 per lane)
    float sred = o0 + o1;
    #pragma unroll
    for (int off = 1; off < 64; off <<= 1) sred += __shfl_xor(sred, off);
    float mu = sred * (1.f / 128.f);
    float d0 = o0 - mu, d1 = o1 - mu;
    float v = d0 * d0 + d1 * d1;
    #pragma unroll
    for (int off = 1; off < 64; off <<= 1) v += __shfl_xor(v, off);
    float rstd = rsqrtf(v * (1.f / 128.f) + 1e-5f);
    o0 = d0 * rstd * ln_g[c0] + ln_b[c0];
    o1 = d1 * rstd * ln_g[c0 + 1] + ln_b[c0 + 1];

    float2 hv = *(const float2*)&hin[(size_t)n * 128 + c0];
    if (FINAL) {
        float r0 = hv.x + o0, r1 = hv.y + o1;
        int g = n >> 9, rr = n & 511;
        if (rr < 511)
            *(float2*)&outp[((size_t)(g * 511 + rr)) * 128 + c0] = make_float2(r0, r1);
    } else {
        o0 = 0.5f * o0 * (1.f + erff(o0 * 0.70710678118f));   // exact GELU
        o1 = 0.5f * o1 * (1.f + erff(o1 * 0.70710678118f));
        hv.x += o0; hv.y += o1;
        *(float2*)&hout[(size_t)n * 128 + c0] = hv;
        uint pk = (uint)f2b(hv.x) | ((uint)f2b(hv.y) << 16);
        *(uint*)&hb[(size_t)n * 128 + c0] = pk;
    }
}

extern "C" void kernel_launch(void* const* d_in, const int* in_sizes, int n_in,
                              void* d_out, int out_size, void* d_ws, size_t ws_size,
                              hipStream_t stream) {
    const float* x        = (const float*)d_in[0];
    const int*   edge_src = (const int*)d_in[1];
    const int*   edge_dst = (const int*)d_in[2];
    const float* edge_attr= (const float*)d_in[3];
    const float* Wl       = (const float*)d_in[4];
    const float* bl       = (const float*)d_in[5];
    const float* Wr       = (const float*)d_in[6];
    const float* br       = (const float*)d_in[7];
    const float* We       = (const float*)d_in[8];
    const float* att      = (const float*)d_in[9];
    const float* bias_p   = (const float*)d_in[10];
    const float* ln_g     = (const float*)d_in[11];
    const float* ln_b     = (const float*)d_in[12];
    float* out = (float*)d_out;

    char* ws = (char*)d_ws;
    float*  h       = (float*)(ws + 0);                 // 33,554,432
    ushort* hb      = (ushort*)(ws + 33554432);         // 16,777,216
    ushort* xl      = (ushort*)(ws + 50331648);         // 16,777,216
    ushort* xr      = (ushort*)(ws + 67108864);         // 16,777,216
    int2*   adj     = (int2*)(ws + 83886080);           //  8,912,896
    int*    row_off = (int*)(ws + 92798976);            //    262,400 (incl pad)
    int*    cnt     = (int*)(ws + 93061376);            //    262,144 (also cursor)
    int*    bsum    = (int*)(ws + 93323520);            //      1,024
    float*  sumbuf  = (float*)(ws + 93324544);          //        256
    ushort* WT      = (ushort*)(ws + 93324800);         //    196,608 (3 layers x 2)

    // 1: transpose weights + zero cnt/sumbuf
    k_init<<<dim3(128, 2, 3), 128, 0, stream>>>(Wl, Wr, WT, cnt, sumbuf);
    // 2: histogram + edge_attr sum
    k_histsum<<<TOTE / 256, 256, 0, stream>>>(edge_dst, edge_attr, cnt, sumbuf);
    // 3-4: scan
    k_scanA<<<NN / 256, 256, 0, stream>>>(cnt, row_off, bsum);
    k_scanC<<<NN / 256, 256, 0, stream>>>(row_off, bsum, cnt);
    // 5: scatter
    k_scatter<<<TOTE / 256, 256, 0, stream>>>(edge_src, edge_dst, edge_attr, sumbuf, cnt, adj);

    // layer 0: GEMM from fp32 x; residual from x
    k_gemm<true><<<NN / 64, 256, 0, stream>>>(x, WT, bl, br, xl, xr);
    k_attn<4, false><<<NN / 4, 256, 0, stream>>>(xl, xr, row_off, adj,
                                                 We, att, bias_p, ln_g, ln_b,
                                                 x, h, hb, nullptr);
    // layer 1
    k_gemm<false><<<NN / 64, 256, 0, stream>>>(hb, WT + 32768, bl + 128, br + 128, xl, xr);
    k_attn<4, false><<<NN / 4, 256, 0, stream>>>(xl, xr, row_off, adj,
                                                 We + 128, att + 128, bias_p + 128,
                                                 ln_g + 128, ln_b + 128,
                                                 h, h, hb, nullptr);
    // layer 2 (final): writes out directly, drops virtual node
    k_gemm<false><<<NN / 64, 256, 0, stream>>>(hb, WT + 65536, bl + 256, br + 256, xl, xr);
    k_attn<1, true><<<NN / 4, 256, 0, stream>>>(xl, xr, row_off, adj,
                                                We + 256, att + 256, bias_p + 256,
                                                ln_g + 256, ln_b + 256,
                                                h, nullptr, nullptr, out);
}

// Round 11
// 632.965 us; speedup vs baseline: 3.0480x; 1.0593x over previous
//
#include <hip/hip_runtime.h>
#include <hip/hip_bf16.h>

typedef unsigned int uint;
typedef unsigned short ushort;

#define NN 65536
#define NE 1048576
#define DD 128
#define TOTE (NE + NN)   // 1114112

__device__ __forceinline__ float b2f(ushort u) {
    uint v = ((uint)u) << 16; float f; __builtin_memcpy(&f, &v, 4); return f;
}
__device__ __forceinline__ ushort f2b(float f) {
    uint x; __builtin_memcpy(&x, &f, 4);
    uint r = (x + 0x7fffu + ((x >> 16) & 1u)) >> 16;
    return (ushort)r;
}

typedef __bf16 bf16x8 __attribute__((ext_vector_type(8)));
typedef float f32x4 __attribute__((ext_vector_type(4)));

// ---------- init: transpose W (fp32 k-major -> bf16 n-major) + zero cnt/sumbuf ----------
__global__ void k_init(const float* __restrict__ Wl, const float* __restrict__ Wr,
                       ushort* __restrict__ WT, int* __restrict__ cnt, float* __restrict__ sumbuf) {
    // grid (128, 2, 3), block 128
    int k = blockIdx.x, n = threadIdx.x, lr = blockIdx.y, layer = blockIdx.z;
    const float* W = (lr ? Wr : Wl) + layer * 16384;
    WT[(layer * 2 + lr) * 16384 + n * 128 + k] = f2b(W[k * 128 + n]);
    int gid = ((blockIdx.z * 2 + blockIdx.y) * 128 + blockIdx.x) * 128 + threadIdx.x;
    if (gid < NN) cnt[gid] = 0;
    if (gid == NN) sumbuf[0] = 0.f;
}

// ---------- histogram by dst (+self loops) fused with edge_attr sum ----------
__global__ void k_histsum(const int* __restrict__ dst, const float* __restrict__ ea,
                          int* __restrict__ cnt, float* __restrict__ sum) {
    __shared__ float red[256];
    int t = threadIdx.x;
    int e = blockIdx.x * 256 + t;     // grid covers TOTE exactly
    int d = (e < NE) ? dst[e] : (e - NE);
    atomicAdd(&cnt[d], 1);
    float s = (e < NE) ? ea[e] : 0.f;
    red[t] = s; __syncthreads();
    for (int o = 128; o > 0; o >>= 1) { if (t < o) red[t] += red[t + o]; __syncthreads(); }
    if (t == 0 && red[0] != 0.f) atomicAdd(sum, red[0]);
}

__global__ void k_scanA(const int* __restrict__ cnt, int* __restrict__ row_off, int* __restrict__ bsum) {
    __shared__ int tmp[256];
    int t = threadIdx.x, i = blockIdx.x * 256 + t;
    int v = cnt[i]; tmp[t] = v; __syncthreads();
    for (int off = 1; off < 256; off <<= 1) {
        int x = (t >= off) ? tmp[t - off] : 0;
        __syncthreads();
        tmp[t] += x;
        __syncthreads();
    }
    row_off[i] = tmp[t] - v;
    if (t == 255) bsum[blockIdx.x] = tmp[255];
}

// scanC with local re-scan of bsum (eliminates scanB dispatch)
__global__ void k_scanC(int* __restrict__ row_off, const int* __restrict__ bsum, int* __restrict__ cursor) {
    __shared__ int tmp[256];
    __shared__ int excl[256];
    int t = threadIdx.x;
    int v = bsum[t]; tmp[t] = v; __syncthreads();
    for (int off = 1; off < 256; off <<= 1) {
        int x = (t >= off) ? tmp[t - off] : 0;
        __syncthreads();
        tmp[t] += x;
        __syncthreads();
    }
    excl[t] = tmp[t] - v;
    __syncthreads();
    int offb = excl[blockIdx.x];
    int i = blockIdx.x * 256 + t;
    int nv = row_off[i] + offb;
    row_off[i] = nv;
    cursor[i] = nv;
    if (i == 0) row_off[NN] = TOTE;
}

// adj.x stores src<<8 (byte offset into bf16 row array: src*128ch*2B)
__global__ void k_scatter(const int* __restrict__ src, const int* __restrict__ dst,
                          const float* __restrict__ ea, const float* __restrict__ sum,
                          int* __restrict__ cursor, int2* __restrict__ adj) {
    int e = blockIdx.x * 256 + threadIdx.x;
    int s, d; float a;
    if (e < NE) { s = src[e]; d = dst[e]; a = ea[e]; }
    else        { s = e - NE; d = s;      a = sum[0] * (1.0f / NE); }
    int pos = atomicAdd(&cursor[d], 1);
    adj[pos] = make_int2(s << 8, __float_as_int(a));
}

// ---------- dual GEMM: xl = src@Wl + bl, xr = src@Wr + br  (bf16 MFMA 16x16x32) ----------
#define LDA 136   // bf16 elems per A row in LDS (272B stride, 16B aligned)

template<bool F32SRC>
__global__ __launch_bounds__(256) void k_gemm(const void* __restrict__ srcv, const ushort* __restrict__ WT,
                                              const float* __restrict__ bl, const float* __restrict__ br,
                                              ushort* __restrict__ xl, ushort* __restrict__ xr) {
    __shared__ ushort A[64 * LDA];
    int t = threadIdx.x;
    int rowbase = blockIdx.x * 64;

    if (F32SRC) {
        const float* src = (const float*)srcv;
        #pragma unroll
        for (int it = 0; it < 8; it++) {
            int idx = it * 256 + t;          // 2048 chunks of 4 floats
            int r = idx >> 5, cc = (idx & 31) * 4;
            float4 v = *(const float4*)&src[(size_t)(rowbase + r) * 128 + cc];
            ushort4 pk; pk.x = f2b(v.x); pk.y = f2b(v.y); pk.z = f2b(v.z); pk.w = f2b(v.w);
            *(ushort4*)&A[r * LDA + cc] = pk;
        }
    } else {
        const ushort* src = (const ushort*)srcv;
        #pragma unroll
        for (int it = 0; it < 4; it++) {
            int idx = it * 256 + t;          // 1024 chunks of 8 bf16
            int r = idx >> 4, cc = (idx & 15) * 8;
            *(bf16x8*)&A[r * LDA + cc] = *(const bf16x8*)&src[(size_t)(rowbase + r) * 128 + cc];
        }
    }
    __syncthreads();

    int wave = t >> 6, lane = t & 63;
    int row16 = lane & 15, quad = lane >> 4;

    f32x4 accl[8], accr[8];
    for (int i = 0; i < 8; i++) {
        accl[i] = (f32x4){0.f, 0.f, 0.f, 0.f};
        accr[i] = (f32x4){0.f, 0.f, 0.f, 0.f};
    }

    for (int ks = 0; ks < 4; ks++) {
        bf16x8 a = *(const bf16x8*)&A[(wave * 16 + row16) * LDA + ks * 32 + quad * 8];
        for (int tc = 0; tc < 8; tc++) {
            int coln = tc * 16 + row16;                 // B fragment: n = lane&15
            bf16x8 b_l = *(const bf16x8*)&WT[coln * 128 + ks * 32 + quad * 8];
            bf16x8 b_r = *(const bf16x8*)&WT[16384 + coln * 128 + ks * 32 + quad * 8];
            accl[tc] = __builtin_amdgcn_mfma_f32_16x16x32_bf16(a, b_l, accl[tc], 0, 0, 0);
            accr[tc] = __builtin_amdgcn_mfma_f32_16x16x32_bf16(a, b_r, accr[tc], 0, 0, 0);
        }
    }

    for (int tc = 0; tc < 8; tc++) {
        int col = tc * 16 + row16;                      // C/D: col = lane&15
        float bbl = bl[col], bbr = br[col];
        for (int r = 0; r < 4; r++) {
            int row = rowbase + wave * 16 + quad * 4 + r;   // C/D: row = quad*4 + reg
            size_t o = (size_t)row * 128 + col;
            xl[o] = f2b(accl[tc][r] + bbl);
            xr[o] = f2b(accr[tc][r] + bbr);
        }
    }
}

// ---------- fused attention, single-gather, max-free softmax, LDS epilogue ----------
// 128-thr block = 2 nodes (1 wave/node; less degree-imbalance coupling than 4).
// Lane = (p=lane>>3: edge slot, cl=lane&7: 16-ch block). adj.x = src byte offset.
// Epilogue: inv-premultiplied partials -> padded LDS tile -> 8 b64 reads/lane
// (replaces 48 shfl_xor). NOTE: keep min-waves<=4; (256,8) spilled (R9, 3x slower).
template<int H, bool FINAL>
__global__ __launch_bounds__(128, 4) void k_attn(
    const ushort* __restrict__ xl, const ushort* __restrict__ xr,
    const int* __restrict__ row_off, const int2* __restrict__ adj,
    const float* __restrict__ We, const float* __restrict__ att,
    const float* __restrict__ bias, const float* __restrict__ ln_g, const float* __restrict__ ln_b,
    const float* __restrict__ hin, float* __restrict__ hout, ushort* __restrict__ hb,
    float* __restrict__ outp)
{
    __shared__ float accbuf[2][8][132];   // [wave][p][128ch + 4 pad] — pad breaks p-stride conflicts

    int wv = threadIdx.x >> 6, lane = threadIdx.x & 63;
    int n = blockIdx.x * 2 + wv;
    int p = lane >> 3;          // edge slot within 8-edge group
    int cl = lane & 7;          // channel block: ch [16*cl, 16*cl+16)
    int c16 = cl * 16;
    const char* xlb = (const char*)xl;

    // register caches
    float we[16], at[16], xrl[16];
    #pragma unroll
    for (int k = 0; k < 16; k++) { we[k] = We[c16 + k]; at[k] = att[c16 + k]; }
    {
        bf16x8 r0 = *(const bf16x8*)&xr[(size_t)n * 128 + c16];
        bf16x8 r1 = *(const bf16x8*)&xr[(size_t)n * 128 + c16 + 8];
        #pragma unroll
        for (int k = 0; k < 8; k++) { xrl[k] = (float)r0[k]; xrl[8 + k] = (float)r1[k]; }
    }

    int s0 = row_off[n], s1 = row_off[n + 1];
    int iters = (s1 - s0 + 7) >> 3;     // >= 1 (self-loop)

    float l_run = 0.f;
    float acc[16];
    #pragma unroll
    for (int k = 0; k < 16; k++) acc[k] = 0.f;

    // prefetch group 0
    int j0 = s0 + p;
    int ja = (j0 < s1) ? j0 : s0;
    int2 pk0 = adj[ja];
    float ea_n = (j0 < s1) ? __int_as_float(pk0.y) : 0.f;
    const char* rp0 = xlb + (size_t)(uint)pk0.x + (cl << 5);
    bf16x8 nx0 = *(const bf16x8*)rp0;
    bf16x8 nx1 = *(const bf16x8*)(rp0 + 16);

    for (int it = 0; it < iters; ++it) {
        bf16x8 x0 = nx0, x1 = nx1;
        float ea_c = ea_n;
        bool valid = (s0 + it * 8 + p) < s1;

        // prefetch next group
        if (it + 1 < iters) {
            int jn = s0 + (it + 1) * 8 + p;
            int jb = (jn < s1) ? jn : s0;
            int2 pk = adj[jb];
            ea_n = (jn < s1) ? __int_as_float(pk.y) : 0.f;
            const char* rp = xlb + (size_t)(uint)pk.x + (cl << 5);
            nx0 = *(const bf16x8*)rp;
            nx1 = *(const bf16x8*)(rp + 16);
        }

        // convert + logit partial over this lane's 16 channels
        float xf[16];
        #pragma unroll
        for (int k = 0; k < 8; k++) { xf[k] = (float)x0[k]; xf[8 + k] = (float)x1[k]; }
        float s = 0.f;
        #pragma unroll
        for (int k = 0; k < 16; k++) {
            float m = xf[k] + fmaf(ea_c, we[k], xrl[k]);
            m = fmaxf(m, 0.2f * m);             // leaky_relu(0.2)
            s = fmaf(m, at[k], s);
        }
        // head reduction across cl lanes of same edge
        s += __shfl_xor(s, 1);
        if (H == 1) { s += __shfl_xor(s, 2); s += __shfl_xor(s, 4); }
        if (!valid) s = -1e30f;

        float e = __expf(s);                 // 0 for invalid; no overflow (|s| small)
        l_run += e;
        #pragma unroll
        for (int k = 0; k < 16; k++) acc[k] = fmaf(e, xf[k], acc[k]);
    }

    // per-head denominator over the 8 edge slots (p)
    l_run += __shfl_xor(l_run, 8);
    l_run += __shfl_xor(l_run, 16);
    l_run += __shfl_xor(l_run, 32);
    float inv = 1.0f / (l_run + 1e-16f);     // matches this lane's channels' head

    // write inv-premultiplied partials to LDS tile
    #pragma unroll
    for (int i = 0; i < 4; i++)
        *(float4*)&accbuf[wv][p][c16 + 4 * i] =
            make_float4(acc[4 * i] * inv, acc[4 * i + 1] * inv,
                        acc[4 * i + 2] * inv, acc[4 * i + 3] * inv);
    __syncthreads();

    // each lane sums its 2 channels across the 8 p-slots
    int c0 = 2 * lane;
    float o0 = 0.f, o1 = 0.f;
    #pragma unroll
    for (int q = 0; q < 8; q++) {
        float2 v = *(float2*)&accbuf[wv][q][c0];
        o0 += v.x; o1 += v.y;
    }
    o0 += bias[c0];
    o1 += bias[c0 + 1];

    // LayerNorm over 128 channels (2 per lane)
    float sred = o0 + o1;
    #pragma unroll
    for (int off = 1; off < 64; off <<= 1) sred += __shfl_xor(sred, off);
    float mu = sred * (1.f / 128.f);
    float d0 = o0 - mu, d1 = o1 - mu;
    float v = d0 * d0 + d1 * d1;
    #pragma unroll
    for (int off = 1; off < 64; off <<= 1) v += __shfl_xor(v, off);
    float rstd = rsqrtf(v * (1.f / 128.f) + 1e-5f);
    o0 = d0 * rstd * ln_g[c0] + ln_b[c0];
    o1 = d1 * rstd * ln_g[c0 + 1] + ln_b[c0 + 1];

    float2 hv = *(const float2*)&hin[(size_t)n * 128 + c0];
    if (FINAL) {
        float r0 = hv.x + o0, r1 = hv.y + o1;
        int g = n >> 9, rr = n & 511;
        if (rr < 511)
            *(float2*)&outp[((size_t)(g * 511 + rr)) * 128 + c0] = make_float2(r0, r1);
    } else {
        o0 = 0.5f * o0 * (1.f + erff(o0 * 0.70710678118f));   // exact GELU
        o1 = 0.5f * o1 * (1.f + erff(o1 * 0.70710678118f));
        hv.x += o0; hv.y += o1;
        *(float2*)&hout[(size_t)n * 128 + c0] = hv;
        uint pk = (uint)f2b(hv.x) | ((uint)f2b(hv.y) << 16);
        *(uint*)&hb[(size_t)n * 128 + c0] = pk;
    }
}

extern "C" void kernel_launch(void* const* d_in, const int* in_sizes, int n_in,
                              void* d_out, int out_size, void* d_ws, size_t ws_size,
                              hipStream_t stream) {
    const float* x        = (const float*)d_in[0];
    const int*   edge_src = (const int*)d_in[1];
    const int*   edge_dst = (const int*)d_in[2];
    const float* edge_attr= (const float*)d_in[3];
    const float* Wl       = (const float*)d_in[4];
    const float* bl       = (const float*)d_in[5];
    const float* Wr       = (const float*)d_in[6];
    const float* br       = (const float*)d_in[7];
    const float* We       = (const float*)d_in[8];
    const float* att      = (const float*)d_in[9];
    const float* bias_p   = (const float*)d_in[10];
    const float* ln_g     = (const float*)d_in[11];
    const float* ln_b     = (const float*)d_in[12];
    float* out = (float*)d_out;

    char* ws = (char*)d_ws;
    float*  h       = (float*)(ws + 0);                 // 33,554,432
    ushort* hb      = (ushort*)(ws + 33554432);         // 16,777,216
    ushort* xl      = (ushort*)(ws + 50331648);         // 16,777,216
    ushort* xr      = (ushort*)(ws + 67108864);         // 16,777,216
    int2*   adj     = (int2*)(ws + 83886080);           //  8,912,896
    int*    row_off = (int*)(ws + 92798976);            //    262,400 (incl pad)
    int*    cnt     = (int*)(ws + 93061376);            //    262,144 (also cursor)
    int*    bsum    = (int*)(ws + 93323520);            //      1,024
    float*  sumbuf  = (float*)(ws + 93324544);          //        256
    ushort* WT      = (ushort*)(ws + 93324800);         //    196,608 (3 layers x 2)

    // 1: transpose weights + zero cnt/sumbuf
    k_init<<<dim3(128, 2, 3), 128, 0, stream>>>(Wl, Wr, WT, cnt, sumbuf);
    // 2: histogram + edge_attr sum
    k_histsum<<<TOTE / 256, 256, 0, stream>>>(edge_dst, edge_attr, cnt, sumbuf);
    // 3-4: scan
    k_scanA<<<NN / 256, 256, 0, stream>>>(cnt, row_off, bsum);
    k_scanC<<<NN / 256, 256, 0, stream>>>(row_off, bsum, cnt);
    // 5: scatter (adj.x = src byte offset)
    k_scatter<<<TOTE / 256, 256, 0, stream>>>(edge_src, edge_dst, edge_attr, sumbuf, cnt, adj);

    // layer 0: GEMM from fp32 x; residual from x
    k_gemm<true><<<NN / 64, 256, 0, stream>>>(x, WT, bl, br, xl, xr);
    k_attn<4, false><<<NN / 2, 128, 0, stream>>>(xl, xr, row_off, adj,
                                                 We, att, bias_p, ln_g, ln_b,
                                                 x, h, hb, nullptr);
    // layer 1
    k_gemm<false><<<NN / 64, 256, 0, stream>>>(hb, WT + 32768, bl + 128, br + 128, xl, xr);
    k_attn<4, false><<<NN / 2, 128, 0, stream>>>(xl, xr, row_off, adj,
                                                 We + 128, att + 128, bias_p + 128,
                                                 ln_g + 128, ln_b + 128,
                                                 h, h, hb, nullptr);
    // layer 2 (final): writes out directly, drops virtual node
    k_gemm<false><<<NN / 64, 256, 0, stream>>>(hb, WT + 65536, bl + 256, br + 256, xl, xr);
    k_attn<1, true><<<NN / 2, 128, 0, stream>>>(xl, xr, row_off, adj,
                                                We + 256, att + 256, bias_p + 256,
                                                ln_g + 256, ln_b + 256,
                                                h, nullptr, nullptr, out);
}

// Round 12
// 630.990 us; speedup vs baseline: 3.0576x; 1.0031x over previous
//
#include <hip/hip_runtime.h>
#include <hip/hip_bf16.h>

typedef unsigned int uint;
typedef unsigned short ushort;

#define NN 65536
#define NE 1048576
#define DD 128
#define TOTE (NE + NN)   // 1114112

__device__ __forceinline__ float b2f(ushort u) {
    uint v = ((uint)u) << 16; float f; __builtin_memcpy(&f, &v, 4); return f;
}
__device__ __forceinline__ ushort f2b(float f) {
    uint x; __builtin_memcpy(&x, &f, 4);
    uint r = (x + 0x7fffu + ((x >> 16) & 1u)) >> 16;
    return (ushort)r;
}

typedef __bf16 bf16x8 __attribute__((ext_vector_type(8)));
typedef float f32x4 __attribute__((ext_vector_type(4)));
typedef float f32x2 __attribute__((ext_vector_type(2)));

// unpack 2 bf16 (packed in uint) -> packed float2, no cvt needed
__device__ __forceinline__ f32x2 bf2f2(uint u) {
    union { uint i; float f; } lo, hi;
    lo.i = u << 16; hi.i = u & 0xffff0000u;
    return (f32x2){lo.f, hi.f};
}

// ---------- init: transpose W (fp32 k-major -> bf16 n-major) + zero cnt/sumbuf ----------
__global__ void k_init(const float* __restrict__ Wl, const float* __restrict__ Wr,
                       ushort* __restrict__ WT, int* __restrict__ cnt, float* __restrict__ sumbuf) {
    // grid (128, 2, 3), block 128
    int k = blockIdx.x, n = threadIdx.x, lr = blockIdx.y, layer = blockIdx.z;
    const float* W = (lr ? Wr : Wl) + layer * 16384;
    WT[(layer * 2 + lr) * 16384 + n * 128 + k] = f2b(W[k * 128 + n]);
    int gid = ((blockIdx.z * 2 + blockIdx.y) * 128 + blockIdx.x) * 128 + threadIdx.x;
    if (gid < NN) cnt[gid] = 0;
    if (gid == NN) sumbuf[0] = 0.f;
}

// ---------- histogram by dst (+self loops) fused with edge_attr sum ----------
__global__ void k_histsum(const int* __restrict__ dst, const float* __restrict__ ea,
                          int* __restrict__ cnt, float* __restrict__ sum) {
    __shared__ float red[256];
    int t = threadIdx.x;
    int e = blockIdx.x * 256 + t;     // grid covers TOTE exactly
    int d = (e < NE) ? dst[e] : (e - NE);
    atomicAdd(&cnt[d], 1);
    float s = (e < NE) ? ea[e] : 0.f;
    red[t] = s; __syncthreads();
    for (int o = 128; o > 0; o >>= 1) { if (t < o) red[t] += red[t + o]; __syncthreads(); }
    if (t == 0 && red[0] != 0.f) atomicAdd(sum, red[0]);
}

__global__ void k_scanA(const int* __restrict__ cnt, int* __restrict__ row_off, int* __restrict__ bsum) {
    __shared__ int tmp[256];
    int t = threadIdx.x, i = blockIdx.x * 256 + t;
    int v = cnt[i]; tmp[t] = v; __syncthreads();
    for (int off = 1; off < 256; off <<= 1) {
        int x = (t >= off) ? tmp[t - off] : 0;
        __syncthreads();
        tmp[t] += x;
        __syncthreads();
    }
    row_off[i] = tmp[t] - v;
    if (t == 255) bsum[blockIdx.x] = tmp[255];
}

// scanC with local re-scan of bsum (eliminates scanB dispatch)
__global__ void k_scanC(int* __restrict__ row_off, const int* __restrict__ bsum, int* __restrict__ cursor) {
    __shared__ int tmp[256];
    __shared__ int excl[256];
    int t = threadIdx.x;
    int v = bsum[t]; tmp[t] = v; __syncthreads();
    for (int off = 1; off < 256; off <<= 1) {
        int x = (t >= off) ? tmp[t - off] : 0;
        __syncthreads();
        tmp[t] += x;
        __syncthreads();
    }
    excl[t] = tmp[t] - v;
    __syncthreads();
    int offb = excl[blockIdx.x];
    int i = blockIdx.x * 256 + t;
    int nv = row_off[i] + offb;
    row_off[i] = nv;
    cursor[i] = nv;
    if (i == 0) row_off[NN] = TOTE;
}

// adj.x stores src<<8 (byte offset into bf16 row array: src*128ch*2B)
__global__ void k_scatter(const int* __restrict__ src, const int* __restrict__ dst,
                          const float* __restrict__ ea, const float* __restrict__ sum,
                          int* __restrict__ cursor, int2* __restrict__ adj) {
    int e = blockIdx.x * 256 + threadIdx.x;
    int s, d; float a;
    if (e < NE) { s = src[e]; d = dst[e]; a = ea[e]; }
    else        { s = e - NE; d = s;      a = sum[0] * (1.0f / NE); }
    int pos = atomicAdd(&cursor[d], 1);
    adj[pos] = make_int2(s << 8, __float_as_int(a));
}

// ---------- dual GEMM: xl = src@Wl + bl, xr = src@Wr + br  (bf16 MFMA 16x16x32) ----------
#define LDA 136   // bf16 elems per A row in LDS (272B stride, 16B aligned)

template<bool F32SRC>
__global__ __launch_bounds__(256) void k_gemm(const void* __restrict__ srcv, const ushort* __restrict__ WT,
                                              const float* __restrict__ bl, const float* __restrict__ br,
                                              ushort* __restrict__ xl, ushort* __restrict__ xr) {
    __shared__ ushort A[64 * LDA];
    int t = threadIdx.x;
    int rowbase = blockIdx.x * 64;

    if (F32SRC) {
        const float* src = (const float*)srcv;
        #pragma unroll
        for (int it = 0; it < 8; it++) {
            int idx = it * 256 + t;          // 2048 chunks of 4 floats
            int r = idx >> 5, cc = (idx & 31) * 4;
            float4 v = *(const float4*)&src[(size_t)(rowbase + r) * 128 + cc];
            ushort4 pk; pk.x = f2b(v.x); pk.y = f2b(v.y); pk.z = f2b(v.z); pk.w = f2b(v.w);
            *(ushort4*)&A[r * LDA + cc] = pk;
        }
    } else {
        const ushort* src = (const ushort*)srcv;
        #pragma unroll
        for (int it = 0; it < 4; it++) {
            int idx = it * 256 + t;          // 1024 chunks of 8 bf16
            int r = idx >> 4, cc = (idx & 15) * 8;
            *(bf16x8*)&A[r * LDA + cc] = *(const bf16x8*)&src[(size_t)(rowbase + r) * 128 + cc];
        }
    }
    __syncthreads();

    int wave = t >> 6, lane = t & 63;
    int row16 = lane & 15, quad = lane >> 4;

    f32x4 accl[8], accr[8];
    for (int i = 0; i < 8; i++) {
        accl[i] = (f32x4){0.f, 0.f, 0.f, 0.f};
        accr[i] = (f32x4){0.f, 0.f, 0.f, 0.f};
    }

    for (int ks = 0; ks < 4; ks++) {
        bf16x8 a = *(const bf16x8*)&A[(wave * 16 + row16) * LDA + ks * 32 + quad * 8];
        for (int tc = 0; tc < 8; tc++) {
            int coln = tc * 16 + row16;                 // B fragment: n = lane&15
            bf16x8 b_l = *(const bf16x8*)&WT[coln * 128 + ks * 32 + quad * 8];
            bf16x8 b_r = *(const bf16x8*)&WT[16384 + coln * 128 + ks * 32 + quad * 8];
            accl[tc] = __builtin_amdgcn_mfma_f32_16x16x32_bf16(a, b_l, accl[tc], 0, 0, 0);
            accr[tc] = __builtin_amdgcn_mfma_f32_16x16x32_bf16(a, b_r, accr[tc], 0, 0, 0);
        }
    }

    for (int tc = 0; tc < 8; tc++) {
        int col = tc * 16 + row16;                      // C/D: col = lane&15
        float bbl = bl[col], bbr = br[col];
        for (int r = 0; r < 4; r++) {
            int row = rowbase + wave * 16 + quad * 4 + r;   // C/D: row = quad*4 + reg
            size_t o = (size_t)row * 128 + col;
            xl[o] = f2b(accl[tc][r] + bbl);
            xr[o] = f2b(accr[tc][r] + bbr);
        }
    }
}

// ---------- fused attention: packed-f32 math, single-gather, max-free softmax, LDS epilogue ----------
// 128-thr block = 2 nodes. Lane = (p=lane>>3: edge slot, cl=lane&7: 16-ch block).
// Inner loops in float2 -> v_pk_fma_f32 (halves VALU). accbuf stride 20/cl-block
// spreads the 8 cl lanes across all 32 banks (2-way max = free).
// NOTE: keep min-waves<=4; (256,8) spilled (R9, 3x slower).
template<int H, bool FINAL>
__global__ __launch_bounds__(128, 4) void k_attn(
    const ushort* __restrict__ xl, const ushort* __restrict__ xr,
    const int* __restrict__ row_off, const int2* __restrict__ adj,
    const float* __restrict__ We, const float* __restrict__ att,
    const float* __restrict__ bias, const float* __restrict__ ln_g, const float* __restrict__ ln_b,
    const float* __restrict__ hin, float* __restrict__ hout, ushort* __restrict__ hb,
    float* __restrict__ outp)
{
    __shared__ float accbuf[2][8][160];   // [wave][p][cl*20 + 0..15] — bank-spread layout

    int wv = threadIdx.x >> 6, lane = threadIdx.x & 63;
    int n = blockIdx.x * 2 + wv;
    int p = lane >> 3;          // edge slot within 8-edge group
    int cl = lane & 7;          // channel block: ch [16*cl, 16*cl+16)
    int c16 = cl * 16;
    const char* xlb = (const char*)xl;

    // register caches (packed pairs)
    f32x2 we2[8], at2[8], xrl2[8];
    #pragma unroll
    for (int k = 0; k < 8; k++) {
        we2[k] = (f32x2){We[c16 + 2 * k], We[c16 + 2 * k + 1]};
        at2[k] = (f32x2){att[c16 + 2 * k], att[c16 + 2 * k + 1]};
    }
    {
        uint4 r0 = *(const uint4*)&xr[(size_t)n * 128 + c16];
        uint4 r1 = *(const uint4*)&xr[(size_t)n * 128 + c16 + 8];
        xrl2[0] = bf2f2(r0.x); xrl2[1] = bf2f2(r0.y); xrl2[2] = bf2f2(r0.z); xrl2[3] = bf2f2(r0.w);
        xrl2[4] = bf2f2(r1.x); xrl2[5] = bf2f2(r1.y); xrl2[6] = bf2f2(r1.z); xrl2[7] = bf2f2(r1.w);
    }

    int s0 = row_off[n], s1 = row_off[n + 1];
    int iters = (s1 - s0 + 7) >> 3;     // >= 1 (self-loop)

    float l_run = 0.f;
    f32x2 acc[8];
    #pragma unroll
    for (int k = 0; k < 8; k++) acc[k] = (f32x2){0.f, 0.f};

    // prefetch group 0
    int j0 = s0 + p;
    int ja = (j0 < s1) ? j0 : s0;
    int2 pk0 = adj[ja];
    float ea_n = (j0 < s1) ? __int_as_float(pk0.y) : 0.f;
    const char* rp0 = xlb + (size_t)(uint)pk0.x + (cl << 5);
    uint4 nu0 = *(const uint4*)rp0;
    uint4 nu1 = *(const uint4*)(rp0 + 16);

    for (int it = 0; it < iters; ++it) {
        uint4 u0 = nu0, u1 = nu1;
        float ea_c = ea_n;
        bool valid = (s0 + it * 8 + p) < s1;

        // prefetch next group
        if (it + 1 < iters) {
            int jn = s0 + (it + 1) * 8 + p;
            int jb = (jn < s1) ? jn : s0;
            int2 pk = adj[jb];
            ea_n = (jn < s1) ? __int_as_float(pk.y) : 0.f;
            const char* rp = xlb + (size_t)(uint)pk.x + (cl << 5);
            nu0 = *(const uint4*)rp;
            nu1 = *(const uint4*)(rp + 16);
        }

        // unpack to packed pairs
        f32x2 xf[8];
        xf[0] = bf2f2(u0.x); xf[1] = bf2f2(u0.y); xf[2] = bf2f2(u0.z); xf[3] = bf2f2(u0.w);
        xf[4] = bf2f2(u1.x); xf[5] = bf2f2(u1.y); xf[6] = bf2f2(u1.z); xf[7] = bf2f2(u1.w);

        // logit partial over this lane's 16 channels (packed)
        f32x2 ea2 = (f32x2){ea_c, ea_c};
        f32x2 s2 = (f32x2){0.f, 0.f};
        #pragma unroll
        for (int k = 0; k < 8; k++) {
            f32x2 m = xf[k] + __builtin_elementwise_fma(ea2, we2[k], xrl2[k]);
            m = __builtin_elementwise_max(m, 0.2f * m);     // leaky_relu(0.2)
            s2 = __builtin_elementwise_fma(m, at2[k], s2);
        }
        float s = s2.x + s2.y;
        // head reduction across cl lanes of same edge
        s += __shfl_xor(s, 1);
        if (H == 1) { s += __shfl_xor(s, 2); s += __shfl_xor(s, 4); }
        if (!valid) s = -1e30f;

        float e = __expf(s);                 // 0 for invalid; no overflow (|s| small)
        l_run += e;
        f32x2 e2 = (f32x2){e, e};
        #pragma unroll
        for (int k = 0; k < 8; k++) acc[k] = __builtin_elementwise_fma(e2, xf[k], acc[k]);
    }

    // per-head denominator over the 8 edge slots (p)
    l_run += __shfl_xor(l_run, 8);
    l_run += __shfl_xor(l_run, 16);
    l_run += __shfl_xor(l_run, 32);
    float inv = 1.0f / (l_run + 1e-16f);     // matches this lane's channels' head

    // write inv-premultiplied partials to LDS tile (bank-spread: base cl*20)
    float* row = &accbuf[wv][p][cl * 20];
    #pragma unroll
    for (int i = 0; i < 4; i++)
        *(float4*)&row[4 * i] = make_float4(acc[2 * i].x * inv, acc[2 * i].y * inv,
                                            acc[2 * i + 1].x * inv, acc[2 * i + 1].y * inv);
    __syncthreads();

    // each lane sums its 2 channels across the 8 p-slots
    int c0 = 2 * lane;
    int rb = (c0 >> 4) * 20 + (c0 & 15);
    float o0 = 0.f, o1 = 0.f;
    #pragma unroll
    for (int q = 0; q < 8; q++) {
        float2 v = *(float2*)&accbuf[wv][q][rb];
        o0 += v.x; o1 += v.y;
    }
    o0 += bias[c0];
    o1 += bias[c0 + 1];

    // LayerNorm over 128 channels (2 per lane)
    float sred = o0 + o1;
    #pragma unroll
    for (int off = 1; off < 64; off <<= 1) sred += __shfl_xor(sred, off);
    float mu = sred * (1.f / 128.f);
    float d0 = o0 - mu, d1 = o1 - mu;
    float v = d0 * d0 + d1 * d1;
    #pragma unroll
    for (int off = 1; off < 64; off <<= 1) v += __shfl_xor(v, off);
    float rstd = rsqrtf(v * (1.f / 128.f) + 1e-5f);
    o0 = d0 * rstd * ln_g[c0] + ln_b[c0];
    o1 = d1 * rstd * ln_g[c0 + 1] + ln_b[c0 + 1];

    float2 hv = *(const float2*)&hin[(size_t)n * 128 + c0];
    if (FINAL) {
        float r0 = hv.x + o0, r1 = hv.y + o1;
        int g = n >> 9, rr = n & 511;
        if (rr < 511)
            *(float2*)&outp[((size_t)(g * 511 + rr)) * 128 + c0] = make_float2(r0, r1);
    } else {
        o0 = 0.5f * o0 * (1.f + erff(o0 * 0.70710678118f));   // exact GELU
        o1 = 0.5f * o1 * (1.f + erff(o1 * 0.70710678118f));
        hv.x += o0; hv.y += o1;
        *(float2*)&hout[(size_t)n * 128 + c0] = hv;
        uint pk = (uint)f2b(hv.x) | ((uint)f2b(hv.y) << 16);
        *(uint*)&hb[(size_t)n * 128 + c0] = pk;
    }
}

extern "C" void kernel_launch(void* const* d_in, const int* in_sizes, int n_in,
                              void* d_out, int out_size, void* d_ws, size_t ws_size,
                              hipStream_t stream) {
    const float* x        = (const float*)d_in[0];
    const int*   edge_src = (const int*)d_in[1];
    const int*   edge_dst = (const int*)d_in[2];
    const float* edge_attr= (const float*)d_in[3];
    const float* Wl       = (const float*)d_in[4];
    const float* bl       = (const float*)d_in[5];
    const float* Wr       = (const float*)d_in[6];
    const float* br       = (const float*)d_in[7];
    const float* We       = (const float*)d_in[8];
    const float* att      = (const float*)d_in[9];
    const float* bias_p   = (const float*)d_in[10];
    const float* ln_g     = (const float*)d_in[11];
    const float* ln_b     = (const float*)d_in[12];
    float* out = (float*)d_out;

    char* ws = (char*)d_ws;
    float*  h       = (float*)(ws + 0);                 // 33,554,432
    ushort* hb      = (ushort*)(ws + 33554432);         // 16,777,216
    ushort* xl      = (ushort*)(ws + 50331648);         // 16,777,216
    ushort* xr      = (ushort*)(ws + 67108864);         // 16,777,216
    int2*   adj     = (int2*)(ws + 83886080);           //  8,912,896
    int*    row_off = (int*)(ws + 92798976);            //    262,400 (incl pad)
    int*    cnt     = (int*)(ws + 93061376);            //    262,144 (also cursor)
    int*    bsum    = (int*)(ws + 93323520);            //      1,024
    float*  sumbuf  = (float*)(ws + 93324544);          //        256
    ushort* WT      = (ushort*)(ws + 93324800);         //    196,608 (3 layers x 2)

    // 1: transpose weights + zero cnt/sumbuf
    k_init<<<dim3(128, 2, 3), 128, 0, stream>>>(Wl, Wr, WT, cnt, sumbuf);
    // 2: histogram + edge_attr sum
    k_histsum<<<TOTE / 256, 256, 0, stream>>>(edge_dst, edge_attr, cnt, sumbuf);
    // 3-4: scan
    k_scanA<<<NN / 256, 256, 0, stream>>>(cnt, row_off, bsum);
    k_scanC<<<NN / 256, 256, 0, stream>>>(row_off, bsum, cnt);
    // 5: scatter (adj.x = src byte offset)
    k_scatter<<<TOTE / 256, 256, 0, stream>>>(edge_src, edge_dst, edge_attr, sumbuf, cnt, adj);

    // layer 0: GEMM from fp32 x; residual from x
    k_gemm<true><<<NN / 64, 256, 0, stream>>>(x, WT, bl, br, xl, xr);
    k_attn<4, false><<<NN / 2, 128, 0, stream>>>(xl, xr, row_off, adj,
                                                 We, att, bias_p, ln_g, ln_b,
                                                 x, h, hb, nullptr);
    // layer 1
    k_gemm<false><<<NN / 64, 256, 0, stream>>>(hb, WT + 32768, bl + 128, br + 128, xl, xr);
    k_attn<4, false><<<NN / 2, 128, 0, stream>>>(xl, xr, row_off, adj,
                                                 We + 128, att + 128, bias_p + 128,
                                                 ln_g + 128, ln_b + 128,
                                                 h, h, hb, nullptr);
    // layer 2 (final): writes out directly, drops virtual node
    k_gemm<false><<<NN / 64, 256, 0, stream>>>(hb, WT + 65536, bl + 256, br + 256, xl, xr);
    k_attn<1, true><<<NN / 2, 128, 0, stream>>>(xl, xr, row_off, adj,
                                                We + 256, att + 256, bias_p + 256,
                                                ln_g + 256, ln_b + 256,
                                                h, nullptr, nullptr, out);
}